// Round 2
// baseline (157.912 us; speedup 1.0000x reference)
//
#include <hip/hip_runtime.h>
#include <hip/hip_bf16.h>
#include <hip/hip_fp8.h>
#include <math.h>

typedef __attribute__((ext_vector_type(4))) int   int4v;
typedef __attribute__((ext_vector_type(8))) int   int8v;
typedef __attribute__((ext_vector_type(4))) float f32x4;

#define BM 128
#define BN 128
#define BK 128   // fp8: one 16x16x128 MFMA consumes the whole staged K-slab

union frag_u { int8v v; int4v h[2]; };

// ---------------------------------------------------------------------------
// prep: UNCHANGED from round 1 (byte-identical) so that when gemm drops below
// it, prep's counters surface in top-5 and can be diagnosed with data.
// ---------------------------------------------------------------------------
__global__ __launch_bounds__(256) void prep_kernel(
    const float* __restrict__ X, const float* __restrict__ S,
    unsigned char* __restrict__ Xq, unsigned char* __restrict__ Sq,
    float* __restrict__ x2, float* __restrict__ s2,
    float* __restrict__ rowsum, int M, int R, int Dv)
{
    const int gid  = blockIdx.x * 256 + threadIdx.x;
    const int nthr = gridDim.x * 256;

    for (int i = gid; i < M; i += nthr) rowsum[i] = 0.f;

    const int lane = threadIdx.x & 63;
    const int wid  = gid >> 6;
    const int nw   = nthr >> 6;

    for (int row = wid; row < R; row += nw) {
        const float* rp;
        unsigned char* op;
        float* sq;
        if (row < M) { rp = X + (size_t)row * Dv;       op = Xq + (size_t)row * Dv;       sq = x2 + row; }
        else         { rp = S + (size_t)(row - M) * Dv; op = Sq + (size_t)(row - M) * Dv; sq = s2 + (row - M); }

        float acc = 0.f;
        for (int k = lane * 8; k < Dv; k += 64 * 8) {
            float4 v0 = *(const float4*)(rp + k);
            float4 v1 = *(const float4*)(rp + k + 4);
            acc += v0.x * v0.x + v0.y * v0.y + v0.z * v0.z + v0.w * v0.w;
            acc += v1.x * v1.x + v1.y * v1.y + v1.z * v1.z + v1.w * v1.w;
            int lo = __builtin_amdgcn_cvt_pk_fp8_f32(v0.x, v0.y, 0, false);
            lo     = __builtin_amdgcn_cvt_pk_fp8_f32(v0.z, v0.w, lo, true);
            int hi = __builtin_amdgcn_cvt_pk_fp8_f32(v1.x, v1.y, 0, false);
            hi     = __builtin_amdgcn_cvt_pk_fp8_f32(v1.z, v1.w, hi, true);
            union { int i2[2]; uint2 u; } pk;
            pk.i2[0] = lo; pk.i2[1] = hi;
            *(uint2*)(op + k) = pk.u;
        }
#pragma unroll
        for (int off = 1; off < 64; off <<= 1)
            acc += __shfl_xor(acc, off, 64);
        if (lane == 0) *sq = acc;
    }
}

// ---------------------------------------------------------------------------
// Fused fp8 GEMM + exp-reduce. 256 threads (4 waves 2x2), tile 128x128.
// NEW: B operand bypasses LDS entirely -> global_load_dwordx4 into registers,
// double-buffered one K-step ahead (reg parity t&1, compile-time indexed).
// A stays in LDS (XOR-chunk swizzle as verified), double-buffered 2x16KB,
// staged 2 steps ahead via global_load_lds with COUNTED vmcnt waits.
// Rationale: old kernel read 64KB/step/block from LDS (~770 cyc) vs 553 cyc
// of MFMA -> LDS-BW-bound. A-only LDS = 32KB read/step (~385 cyc) < MFMA.
//
// vmcnt ledger (NT=4; issue order: pro {A0,B0,A1}; iter t: {B(t+1)}, {A(t+2)}):
//   t=0 wait(4): retires A0,B0 (A1 flying)           [NT==1: wait(0)]
//   t=1 wait(12): outstanding {A1,B1,A2}=16 -> A1 ok
//   t=2 wait(12): outstanding {A2,B2,A3}=16 -> A2 ok
//   t=3 wait(8):  outstanding {A3,B3}=12    -> A3 ok
// B(t) regs are waited by the compiler's own precise vmcnt before MFMA(t).
// All asm waits only ever over-wait under any compiler reordering (checked).
// ---------------------------------------------------------------------------
template<int DVC>
__global__ __launch_bounds__(256, 2) void kde_gemm_kernel(
    const unsigned char* __restrict__ Xq,   // [M][D] fp8 e4m3
    const unsigned char* __restrict__ Sq,   // [N][D] fp8 e4m3
    const float* __restrict__ x2,
    const float* __restrict__ s2,
    const float* __restrict__ scale_p,
    float* __restrict__ rowsum,
    int M, int N, int Dv)
{
    const int D  = DVC ? DVC : Dv;
    const int NT = D / BK;

    __shared__ char smem[32768];   // A double-buffer: 2 x 16KB (epilogue reuses)

    const int tid  = threadIdx.x;
    const int wave = tid >> 6;
    const int lane = tid & 63;
    const int quad = lane >> 4;
    const int l16  = lane & 15;

    const int m0 = blockIdx.x * BM;
    const int n0 = blockIdx.y * BN;
    const int wm = (wave & 1) * 64;   // wave's 64x64 quadrant
    const int wn = (wave >> 1) * 64;

    const float sc = *scale_p;

    f32x4 acc[4][4] = {};

    // ---- A staging (unchanged addressing, A only): thread t stages row
    // wave*8+(lane>>3)+rd*32, global 16B-chunk (lane&7)^(row&7), LDS linear.
    const int srow0 = wave * 8 + (lane >> 3);
    const int cg    = (lane & 7) ^ (lane >> 3);
    const unsigned char* gA = Xq + (size_t)(m0 + srow0) * D + cg * 16;

    auto stageA = [&](int slab, int bufo) {
        const size_t ko = (size_t)slab * BK;
#pragma unroll
        for (int rd = 0; rd < 4; ++rd)
            __builtin_amdgcn_global_load_lds(
                (const __attribute__((address_space(1))) void*)(gA + (size_t)rd * 32 * D + ko),
                (__attribute__((address_space(3))) void*)(smem + bufo + rd * 4096 + wave * 1024),
                16, 0, 0);
    };

    // ---- B fragments direct from global. Same (row,k)<->(lane,reg) mapping
    // the LDS path delivered: lane l16 = row wn+ni*16+l16, k = quad*32+{0..31}.
    const unsigned char* gBr = Sq + (size_t)(n0 + wn + l16) * D + quad * 32;
    frag_u bfr[2][4];

    auto loadB = [&](int slab, int p) {
#pragma unroll
        for (int ni = 0; ni < 4; ++ni) {
            bfr[p][ni].h[0] = *(const int4v*)(gBr + (size_t)ni * 16 * D + (size_t)slab * BK);
            bfr[p][ni].h[1] = *(const int4v*)(gBr + (size_t)ni * 16 * D + (size_t)slab * BK + 16);
        }
    };

    // prologue: issue order A0, B0, A1 (asm waits are safe under reorder)
    stageA(0, 0);
    loadB(0, 0);
    if (NT > 1) stageA(1, 16384);

    // A-fragment LDS offsets (k0-invariant; collapse to base + immediates)
    const int e     = l16 & 7;
    const int offLo = ((2 * quad)     ^ e) * 16;
    const int offHi = ((2 * quad + 1) ^ e) * 16;
    int aOff[4];
#pragma unroll
    for (int i = 0; i < 4; ++i)
        aOff[i] = (wm + i * 16 + l16) * 128;

#pragma unroll
    for (int t = 0; t < NT; ++t) {
        // ---- wait: A(t) staged (counted; see ledger above)
        if (t == 0) {
            if (NT > 1) asm volatile("s_waitcnt vmcnt(4)" ::: "memory");
            else        asm volatile("s_waitcnt vmcnt(0)" ::: "memory");
        } else if (t == NT - 1) {
            asm volatile("s_waitcnt vmcnt(8)" ::: "memory");
        } else {
            asm volatile("s_waitcnt vmcnt(12)" ::: "memory");
        }
        __builtin_amdgcn_s_barrier();   // buf[t&1] staged for all waves

        const int bufo = (t & 1) * 16384;
        frag_u a_frag[4];
#pragma unroll
        for (int mi = 0; mi < 4; ++mi) {
            a_frag[mi].h[0] = *(const int4v*)(smem + bufo + aOff[mi] + offLo);
            a_frag[mi].h[1] = *(const int4v*)(smem + bufo + aOff[mi] + offHi);
        }

        // issue next step's B loads (regs; no LDS hazard). Pinned before the
        // asm memory-clobber below, after the barrier above.
        if (t + 1 < NT) loadB(t + 1, (t + 1) & 1);

        if (t + 2 < NT) {
            // all waves' A-frag ds_reads done before buf[t&1] is overwritten
            asm volatile("s_waitcnt lgkmcnt(0)" ::: "memory");
            __builtin_amdgcn_sched_barrier(0);
            __builtin_amdgcn_s_barrier();
            stageA(t + 2, bufo);        // async; hides under MFMAs below
        }

        const int p = t & 1;
        __builtin_amdgcn_s_setprio(1);
#pragma unroll
        for (int mi = 0; mi < 4; ++mi)
#pragma unroll
            for (int ni = 0; ni < 4; ++ni)
                acc[mi][ni] = __builtin_amdgcn_mfma_scale_f32_16x16x128_f8f6f4(
                    a_frag[mi].v, bfr[p][ni].v, acc[mi][ni],
                    0, 0,                     // cbsz=fp8 e4m3, blgp=fp8 e4m3
                    0, 0x7F7F7F7F,            // A scales: unity E8M0
                    0, 0x7F7F7F7F);           // B scales: unity
        __builtin_amdgcn_s_setprio(0);
    }

    // ---- epilogue (unchanged). C layout: col = l16 (-> n), row = quad*4+reg.
    __syncthreads();  // drains vm/lgkm; safe to reuse LDS (wred 20KB <= 32KB)
    float* wred = (float*)smem + wave * (64 * 20);  // 5120 B per wave

    float s2v[4];
#pragma unroll
    for (int ni = 0; ni < 4; ++ni)
        s2v[ni] = s2[n0 + wn + ni * 16 + l16];

#pragma unroll
    for (int mi = 0; mi < 4; ++mi) {
#pragma unroll
        for (int r = 0; r < 4; ++r) {
            const int rowL = mi * 16 + quad * 4 + r;
            const float xv = x2[m0 + wm + rowL];
            float sum = 0.f;
#pragma unroll
            for (int ni = 0; ni < 4; ++ni) {
                float d2 = xv + s2v[ni] - 2.0f * acc[mi][ni][r];
                d2 = fmaxf(d2, 0.f);
                sum += __expf(-sc * d2);
            }
            wred[rowL * 20 + l16] = sum;
        }
    }
    __syncthreads();  // order LDS writes before cross-lane reads

    float4 p0 = *(float4*)(wred + lane * 20 + 0);
    float4 p1 = *(float4*)(wred + lane * 20 + 4);
    float4 p2 = *(float4*)(wred + lane * 20 + 8);
    float4 p3 = *(float4*)(wred + lane * 20 + 12);
    float s = (p0.x + p0.y + p0.z + p0.w) + (p1.x + p1.y + p1.z + p1.w)
            + (p2.x + p2.y + p2.z + p2.w) + (p3.x + p3.y + p3.z + p3.w);
    atomicAdd(&rowsum[m0 + wm + lane], s);
}

// ---------------------------------------------------------------------------
__global__ void finalize_kernel(const float* __restrict__ rowsum,
                                const float* __restrict__ scale_p,
                                float* __restrict__ out, int M, int N, int Dv) {
    const int m = blockIdx.x * 256 + threadIdx.x;
    if (m < M) {
        const float sc = *scale_p;
        const float cst = -logf((float)N) + 0.5f * (float)Dv * logf(sc / 3.14159265358979f);
        out[m] = logf(rowsum[m]) + cst;
    }
}

// ---------------------------------------------------------------------------
extern "C" void kernel_launch(void* const* d_in, const int* in_sizes, int n_in,
                              void* d_out, int out_size, void* d_ws, size_t ws_size,
                              hipStream_t stream) {
    const float* X       = (const float*)d_in[0];
    const float* S       = (const float*)d_in[1];
    const float* scale_p = (const float*)d_in[2];
    float* out = (float*)d_out;

    const int M  = out_size;            // 8192
    const int Dv = in_sizes[0] / M;     // 512
    const int N  = in_sizes[1] / Dv;    // 8192

    char* ws = (char*)d_ws;
    unsigned char* Xq = (unsigned char*)ws;
    unsigned char* Sq = (unsigned char*)(ws + (size_t)M * Dv);
    float* x2     = (float*)(ws + (size_t)M * Dv + (size_t)N * Dv);
    float* s2     = x2 + M;
    float* rowsum = s2 + N;

    prep_kernel<<<2048, 256, 0, stream>>>(X, S, Xq, Sq, x2, s2, rowsum, M, M + N, Dv);

    dim3 grid(M / BM, N / BN);
    if (Dv == 512)
        kde_gemm_kernel<512><<<grid, 256, 0, stream>>>(Xq, Sq, x2, s2, scale_p, rowsum, M, N, Dv);
    else
        kde_gemm_kernel<0><<<grid, 256, 0, stream>>>(Xq, Sq, x2, s2, scale_p, rowsum, M, N, Dv);

    finalize_kernel<<<(M + 255) / 256, 256, 0, stream>>>(rowsum, scale_p, out, M, N, Dv);
}

// Round 3
// 127.844 us; speedup vs baseline: 1.2352x; 1.2352x over previous
//
#include <hip/hip_runtime.h>
#include <hip/hip_bf16.h>
#include <hip/hip_fp8.h>
#include <math.h>

typedef __attribute__((ext_vector_type(4))) int   int4v;
typedef __attribute__((ext_vector_type(8))) int   int8v;
typedef __attribute__((ext_vector_type(4))) float f32x4;

#define BM 128
#define BN 128
#define BK 128   // fp8: one 16x16x128 MFMA consumes the whole staged K-slab

union frag_u { int8v v; int4v h[2]; };

// ---------------------------------------------------------------------------
// prep: 2048 blocks x 256 threads, one wave per row per iter.
// X rows -> Xq ROW-MAJOR fp8 (A path still stages via global_load_lds).
// S rows -> Sq FRAGMENT-PACKED fp8: byte for (row, k) lands at
//   ((g*NSLAB+slab)*2+half)*1024 + (quad*16+l16)*16 + b
//   g=row>>4, l16=row&15, slab=k>>7, quad=(k>>5)&3, half=(k>>4)&1, b=k&15
// so a gemm wave's B-fragment load is base + lane*16 : 1 KB contiguous.
// Also exact fp32 row norms and rowsum[M] zeroing.
// ---------------------------------------------------------------------------
__global__ __launch_bounds__(256) void prep_kernel(
    const float* __restrict__ X, const float* __restrict__ S,
    unsigned char* __restrict__ Xq, unsigned char* __restrict__ Sq,
    float* __restrict__ x2, float* __restrict__ s2,
    float* __restrict__ rowsum, int M, int R, int Dv)
{
    const int gid  = blockIdx.x * 256 + threadIdx.x;
    const int nthr = gridDim.x * 256;
    const int nslab = Dv >> 7;

    for (int i = gid; i < M; i += nthr) rowsum[i] = 0.f;

    const int lane = threadIdx.x & 63;
    const int wid  = gid >> 6;
    const int nw   = nthr >> 6;

    for (int row = wid; row < R; row += nw) {
        const float* rp;
        float* sq;
        unsigned char* opX = nullptr;
        int rr = 0;
        if (row < M) { rp = X + (size_t)row * Dv; opX = Xq + (size_t)row * Dv; sq = x2 + row; }
        else         { rr = row - M; rp = S + (size_t)rr * Dv; sq = s2 + rr; }

        float acc = 0.f;
        for (int k = lane * 8; k < Dv; k += 64 * 8) {
            float4 v0 = *(const float4*)(rp + k);
            float4 v1 = *(const float4*)(rp + k + 4);
            acc += v0.x * v0.x + v0.y * v0.y + v0.z * v0.z + v0.w * v0.w;
            acc += v1.x * v1.x + v1.y * v1.y + v1.z * v1.z + v1.w * v1.w;
            int lo = __builtin_amdgcn_cvt_pk_fp8_f32(v0.x, v0.y, 0, false);
            lo     = __builtin_amdgcn_cvt_pk_fp8_f32(v0.z, v0.w, lo, true);
            int hi = __builtin_amdgcn_cvt_pk_fp8_f32(v1.x, v1.y, 0, false);
            hi     = __builtin_amdgcn_cvt_pk_fp8_f32(v1.z, v1.w, hi, true);
            union { int i2[2]; uint2 u; } pk;
            pk.i2[0] = lo; pk.i2[1] = hi;
            if (row < M) {
                *(uint2*)(opX + k) = pk.u;
            } else {
                const int slab = k >> 7;
                const int rem  = k & 127;              // quad=rem>>5 half=(rem>>4)&1 b=rem&15
                const size_t off =
                    ((size_t)(((rr >> 4) * nslab + slab) * 2 + ((rem >> 4) & 1)) << 10)
                    + (size_t)(((rem >> 5) * 16 + (rr & 15)) << 4) + (rem & 15);
                *(uint2*)(Sq + off) = pk.u;
            }
        }
#pragma unroll
        for (int off = 1; off < 64; off <<= 1)
            acc += __shfl_xor(acc, off, 64);
        if (lane == 0) *sq = acc;
    }
}

// ---------------------------------------------------------------------------
// Fused fp8 GEMM + exp-reduce. 256 threads (4 waves 2x2), tile 128x128.
// A: LDS (XOR-chunk swizzle, verified), 2x16KB dbuf, staged 2 slabs ahead
//    via global_load_lds (4 vm-ops/wave/slab).
// B: registers, direct from FRAGMENT-PACKED Sq (see prep). Each load is
//    base + lane*16 -> 1 KB contiguous per instr (8 vm-ops/wave/slab),
//    double-buffered 1 slab ahead. Round-2's failure was this same path on
//    row-major Sq (16-row x 512B-stride scatter) -> packed layout fixes it.
// vmcnt ledger (issue order pro: A0(4),B0(8),A1(4); iter t: B(t+1)(8),
// A(t+2)(4)): outstanding at top of any non-final t = A(t),B(t),A(t+1) = 16
// -> wait vmcnt(4) retires A(t)+B(t). Final t -> vmcnt(0). NT==1 -> vmcnt(0).
// ---------------------------------------------------------------------------
template<int DVC>
__global__ __launch_bounds__(256, 2) void kde_gemm_kernel(
    const unsigned char* __restrict__ Xq,   // [M][D] fp8 row-major
    const unsigned char* __restrict__ Sq,   // fragment-packed fp8
    const float* __restrict__ x2,
    const float* __restrict__ s2,
    const float* __restrict__ scale_p,
    float* __restrict__ rowsum,
    int M, int N, int Dv)
{
    const int D     = DVC ? DVC : Dv;
    const int NT    = D / BK;
    const int NSLAB = D >> 7;

    __shared__ char smem[32768];   // A double-buffer: 2 x 16KB (epilogue reuses)

    const int tid  = threadIdx.x;
    const int wave = tid >> 6;
    const int lane = tid & 63;
    const int quad = lane >> 4;
    const int l16  = lane & 15;

    const int m0 = blockIdx.x * BM;
    const int n0 = blockIdx.y * BN;
    const int wm = (wave & 1) * 64;   // wave's 64x64 quadrant
    const int wn = (wave >> 1) * 64;

    const float sc = *scale_p;

    f32x4 acc[4][4] = {};

    // ---- A staging (unchanged): thread t stages row wave*8+(lane>>3)+rd*32,
    // global 16B-chunk (lane&7)^(row&7), LDS linear.
    const int srow0 = wave * 8 + (lane >> 3);
    const int cg    = (lane & 7) ^ (lane >> 3);
    const unsigned char* gA = Xq + (size_t)(m0 + srow0) * D + cg * 16;

    auto stageA = [&](int slab, int bufo) {
        const size_t ko = (size_t)slab * BK;
#pragma unroll
        for (int rd = 0; rd < 4; ++rd)
            __builtin_amdgcn_global_load_lds(
                (const __attribute__((address_space(1))) void*)(gA + (size_t)rd * 32 * D + ko),
                (__attribute__((address_space(3))) void*)(smem + bufo + rd * 4096 + wave * 1024),
                16, 0, 0);
    };

    // ---- B fragments from packed Sq: for (ni, slab) the wave reads
    // 2 x 1KB contiguous (halves), lane offset = lane*16.
    const unsigned char* gBr = Sq + ((size_t)((n0 + wn) >> 4) * NSLAB) * 2048 + lane * 16;
    frag_u bfr[2][4];

    auto loadB = [&](int slab, int p) {
#pragma unroll
        for (int ni = 0; ni < 4; ++ni) {
            const unsigned char* c = gBr + (size_t)(ni * NSLAB + slab) * 2048;
            bfr[p][ni].h[0] = *(const int4v*)(c);
            bfr[p][ni].h[1] = *(const int4v*)(c + 1024);
        }
    };

    // prologue: A0, B0, A1
    stageA(0, 0);
    loadB(0, 0);
    if (NT > 1) stageA(1, 16384);

    // A-fragment LDS offsets (k0-invariant)
    const int e     = l16 & 7;
    const int offLo = ((2 * quad)     ^ e) * 16;
    const int offHi = ((2 * quad + 1) ^ e) * 16;
    int aOff[4];
#pragma unroll
    for (int i = 0; i < 4; ++i)
        aOff[i] = (wm + i * 16 + l16) * 128;

#pragma unroll
    for (int t = 0; t < NT; ++t) {
        if (t == NT - 1) asm volatile("s_waitcnt vmcnt(0)" ::: "memory");
        else             asm volatile("s_waitcnt vmcnt(4)" ::: "memory");
        __builtin_amdgcn_s_barrier();   // buf[t&1] staged for all waves

        // issue next slab's B loads first (longest latency, no dependencies)
        if (t + 1 < NT) loadB(t + 1, (t + 1) & 1);

        const int bufo = (t & 1) * 16384;
        frag_u a_frag[4];
#pragma unroll
        for (int mi = 0; mi < 4; ++mi) {
            a_frag[mi].h[0] = *(const int4v*)(smem + bufo + aOff[mi] + offLo);
            a_frag[mi].h[1] = *(const int4v*)(smem + bufo + aOff[mi] + offHi);
        }

        if (t + 2 < NT) {
            // all waves' A-frag ds_reads done before buf[t&1] is overwritten
            asm volatile("s_waitcnt lgkmcnt(0)" ::: "memory");
            __builtin_amdgcn_sched_barrier(0);
            __builtin_amdgcn_s_barrier();
            stageA(t + 2, bufo);        // async; hides under MFMAs below
        }

        const int p = t & 1;
        __builtin_amdgcn_s_setprio(1);
#pragma unroll
        for (int mi = 0; mi < 4; ++mi)
#pragma unroll
            for (int ni = 0; ni < 4; ++ni)
                acc[mi][ni] = __builtin_amdgcn_mfma_scale_f32_16x16x128_f8f6f4(
                    a_frag[mi].v, bfr[p][ni].v, acc[mi][ni],
                    0, 0,                     // cbsz=fp8 e4m3, blgp=fp8 e4m3
                    0, 0x7F7F7F7F,            // A scales: unity E8M0
                    0, 0x7F7F7F7F);           // B scales: unity
        __builtin_amdgcn_s_setprio(0);
    }

    // ---- epilogue (unchanged). C layout: col = l16 (-> n), row = quad*4+reg.
    __syncthreads();  // drains vm/lgkm; safe to reuse LDS (wred 20KB <= 32KB)
    float* wred = (float*)smem + wave * (64 * 20);  // 5120 B per wave

    float s2v[4];
#pragma unroll
    for (int ni = 0; ni < 4; ++ni)
        s2v[ni] = s2[n0 + wn + ni * 16 + l16];

#pragma unroll
    for (int mi = 0; mi < 4; ++mi) {
#pragma unroll
        for (int r = 0; r < 4; ++r) {
            const int rowL = mi * 16 + quad * 4 + r;
            const float xv = x2[m0 + wm + rowL];
            float sum = 0.f;
#pragma unroll
            for (int ni = 0; ni < 4; ++ni) {
                float d2 = xv + s2v[ni] - 2.0f * acc[mi][ni][r];
                d2 = fmaxf(d2, 0.f);
                sum += __expf(-sc * d2);
            }
            wred[rowL * 20 + l16] = sum;
        }
    }
    __syncthreads();  // order LDS writes before cross-lane reads

    float4 p0 = *(float4*)(wred + lane * 20 + 0);
    float4 p1 = *(float4*)(wred + lane * 20 + 4);
    float4 p2 = *(float4*)(wred + lane * 20 + 8);
    float4 p3 = *(float4*)(wred + lane * 20 + 12);
    float s = (p0.x + p0.y + p0.z + p0.w) + (p1.x + p1.y + p1.z + p1.w)
            + (p2.x + p2.y + p2.z + p2.w) + (p3.x + p3.y + p3.z + p3.w);
    atomicAdd(&rowsum[m0 + wm + lane], s);
}

// ---------------------------------------------------------------------------
__global__ void finalize_kernel(const float* __restrict__ rowsum,
                                const float* __restrict__ scale_p,
                                float* __restrict__ out, int M, int N, int Dv) {
    const int m = blockIdx.x * 256 + threadIdx.x;
    if (m < M) {
        const float sc = *scale_p;
        const float cst = -logf((float)N) + 0.5f * (float)Dv * logf(sc / 3.14159265358979f);
        out[m] = logf(rowsum[m]) + cst;
    }
}

// ---------------------------------------------------------------------------
extern "C" void kernel_launch(void* const* d_in, const int* in_sizes, int n_in,
                              void* d_out, int out_size, void* d_ws, size_t ws_size,
                              hipStream_t stream) {
    const float* X       = (const float*)d_in[0];
    const float* S       = (const float*)d_in[1];
    const float* scale_p = (const float*)d_in[2];
    float* out = (float*)d_out;

    const int M  = out_size;            // 8192
    const int Dv = in_sizes[0] / M;     // 512
    const int N  = in_sizes[1] / Dv;    // 8192

    char* ws = (char*)d_ws;
    unsigned char* Xq = (unsigned char*)ws;
    unsigned char* Sq = (unsigned char*)(ws + (size_t)M * Dv);
    float* x2     = (float*)(ws + (size_t)M * Dv + (size_t)N * Dv);
    float* s2     = x2 + M;
    float* rowsum = s2 + N;

    prep_kernel<<<2048, 256, 0, stream>>>(X, S, Xq, Sq, x2, s2, rowsum, M, M + N, Dv);

    dim3 grid(M / BM, N / BN);
    if (Dv == 512)
        kde_gemm_kernel<512><<<grid, 256, 0, stream>>>(Xq, Sq, x2, s2, scale_p, rowsum, M, N, Dv);
    else
        kde_gemm_kernel<0><<<grid, 256, 0, stream>>>(Xq, Sq, x2, s2, scale_p, rowsum, M, N, Dv);

    finalize_kernel<<<(M + 255) / 256, 256, 0, stream>>>(rowsum, scale_p, out, M, N, Dv);
}

// Round 4
// 119.620 us; speedup vs baseline: 1.3201x; 1.0688x over previous
//
#include <hip/hip_runtime.h>
#include <hip/hip_bf16.h>
#include <hip/hip_fp8.h>
#include <math.h>

typedef __attribute__((ext_vector_type(4))) int   int4v;
typedef __attribute__((ext_vector_type(8))) int   int8v;
typedef __attribute__((ext_vector_type(4))) float f32x4;

#define BM 128
#define BN 128
#define BK 128   // fp8: one 16x16x128 MFMA consumes the whole staged K-slab

union frag_u { int8v v; int4v h[2]; };

// ---------------------------------------------------------------------------
// prep: 2048 blocks x 256 threads, one wave per row per iter. Row-major fp8
// out for BOTH X and S (gemm stages both from row-major via XOR-chunk
// global source). HW packed cvt (v_cvt_pk_fp8_f32) + exact fp32 ||row||^2.
// Also zeroes rowsum[M].
// ---------------------------------------------------------------------------
__global__ __launch_bounds__(256) void prep_kernel(
    const float* __restrict__ X, const float* __restrict__ S,
    unsigned char* __restrict__ Xq, unsigned char* __restrict__ Sq,
    float* __restrict__ x2, float* __restrict__ s2,
    float* __restrict__ rowsum, int M, int R, int Dv)
{
    const int gid  = blockIdx.x * 256 + threadIdx.x;
    const int nthr = gridDim.x * 256;

    for (int i = gid; i < M; i += nthr) rowsum[i] = 0.f;

    const int lane = threadIdx.x & 63;
    const int wid  = gid >> 6;
    const int nw   = nthr >> 6;

    for (int row = wid; row < R; row += nw) {
        const float* rp;
        unsigned char* op;
        float* sq;
        if (row < M) { rp = X + (size_t)row * Dv;       op = Xq + (size_t)row * Dv;       sq = x2 + row; }
        else         { rp = S + (size_t)(row - M) * Dv; op = Sq + (size_t)(row - M) * Dv; sq = s2 + (row - M); }

        float acc = 0.f;
        for (int k = lane * 8; k < Dv; k += 64 * 8) {
            float4 v0 = *(const float4*)(rp + k);
            float4 v1 = *(const float4*)(rp + k + 4);
            acc += v0.x * v0.x + v0.y * v0.y + v0.z * v0.z + v0.w * v0.w;
            acc += v1.x * v1.x + v1.y * v1.y + v1.z * v1.z + v1.w * v1.w;
            int lo = __builtin_amdgcn_cvt_pk_fp8_f32(v0.x, v0.y, 0, false);
            lo     = __builtin_amdgcn_cvt_pk_fp8_f32(v0.z, v0.w, lo, true);
            int hi = __builtin_amdgcn_cvt_pk_fp8_f32(v1.x, v1.y, 0, false);
            hi     = __builtin_amdgcn_cvt_pk_fp8_f32(v1.z, v1.w, hi, true);
            union { int i2[2]; uint2 u; } pk;
            pk.i2[0] = lo; pk.i2[1] = hi;
            *(uint2*)(op + k) = pk.u;
        }
#pragma unroll
        for (int off = 1; off < 64; off <<= 1)
            acc += __shfl_xor(acc, off, 64);
        if (lane == 0) *sq = acc;
    }
}

// ---------------------------------------------------------------------------
// Fused fp8 GEMM + exp-reduce — EXACT round-0 champion structure (48.5 us):
// 256 threads (4 waves 2x2), tile 128x128, BK=128, single 32KB LDS buffer,
// two __syncthreads per K-step, both A and B staged via global_load_lds with
// XOR-chunk swizzle (LDS dest linear, swizzle in global source address).
// ONE isolated change vs round-0: fragment LDS reads go DIRECTLY into the
// MFMA operand registers (frag_u union, 2x ds_read_b128 per fragment) —
// removes the ~64 v_mov_b32/wave/slab the vector-constructor assembly cost.
// (Rounds 1-3 eliminated: not drains [r1 null], not LDS volume [r3 null],
// not bank conflicts [r3 halved, null] -> remaining VALU overhead is movs.)
// ---------------------------------------------------------------------------
template<int DVC>
__global__ __launch_bounds__(256, 3) void kde_gemm_kernel(
    const unsigned char* __restrict__ Xq,   // [M][D] fp8 e4m3
    const unsigned char* __restrict__ Sq,   // [N][D] fp8 e4m3
    const float* __restrict__ x2,
    const float* __restrict__ s2,
    const float* __restrict__ scale_p,
    float* __restrict__ rowsum,
    int M, int N, int Dv)
{
    const int D = DVC ? DVC : Dv;

    __shared__ char smem[32768];
    unsigned char* As = (unsigned char*)smem;            // [128][128] fp8 16 KB
    unsigned char* Bs = (unsigned char*)(smem + 16384);  // [128][128] fp8 16 KB

    const int tid  = threadIdx.x;
    const int wave = tid >> 6;
    const int lane = tid & 63;
    const int quad = lane >> 4;
    const int l16  = lane & 15;

    const int m0 = blockIdx.x * BM;
    const int n0 = blockIdx.y * BN;
    const int wm = (wave & 1) * 64;   // wave's 64x64 quadrant
    const int wn = (wave >> 1) * 64;

    const float sc = *scale_p;

    f32x4 acc[4][4] = {};

    // staging: round rd covers rows rd*32..rd*32+31 (128 B each). Thread t:
    // row = rd*32 + (t>>3), fetches GLOBAL 16B-chunk (t&7)^(row&7) into
    // physical slot t&7; LDS dest = rd*4096 + t*16 (linear in lane).
    const int srow0 = wave * 8 + (lane >> 3);
    const int cg    = (lane & 7) ^ (lane >> 3);   // (row&7) == lane>>3
    const unsigned char* gA = Xq + (size_t)(m0 + srow0) * D + cg * 16;
    const unsigned char* gB = Sq + (size_t)(n0 + srow0) * D + cg * 16;

    // fragment LDS offsets (k0-invariant; base + 16-bit immediates after unroll)
    const int e     = l16 & 7;
    const int offLo = ((2 * quad)     ^ e) * 16;
    const int offHi = ((2 * quad + 1) ^ e) * 16;
    int aOff[4], bOff[4];
#pragma unroll
    for (int i = 0; i < 4; ++i) {
        aOff[i] = (wm + i * 16 + l16) * 128;
        bOff[i] = 16384 + (wn + i * 16 + l16) * 128;
    }

#pragma unroll
    for (int k0 = 0; k0 < D; k0 += BK) {
        __syncthreads();  // prev iter's ds_reads done before overwrite
#pragma unroll
        for (int rd = 0; rd < 4; ++rd)
            __builtin_amdgcn_global_load_lds(
                (const __attribute__((address_space(1))) void*)(gA + (size_t)rd * 32 * D + k0),
                (__attribute__((address_space(3))) void*)(smem + rd * 4096 + wave * 1024),
                16, 0, 0);
#pragma unroll
        for (int rd = 0; rd < 4; ++rd)
            __builtin_amdgcn_global_load_lds(
                (const __attribute__((address_space(1))) void*)(gB + (size_t)rd * 32 * D + k0),
                (__attribute__((address_space(3))) void*)(smem + 16384 + rd * 4096 + wave * 1024),
                16, 0, 0);
        __syncthreads();  // staging drained

        frag_u a_frag[4], b_frag[4];
#pragma unroll
        for (int mi = 0; mi < 4; ++mi) {
            a_frag[mi].h[0] = *(const int4v*)(smem + aOff[mi] + offLo);
            a_frag[mi].h[1] = *(const int4v*)(smem + aOff[mi] + offHi);
        }
#pragma unroll
        for (int ni = 0; ni < 4; ++ni) {
            b_frag[ni].h[0] = *(const int4v*)(smem + bOff[ni] + offLo);
            b_frag[ni].h[1] = *(const int4v*)(smem + bOff[ni] + offHi);
        }
#pragma unroll
        for (int mi = 0; mi < 4; ++mi)
#pragma unroll
            for (int ni = 0; ni < 4; ++ni)
                acc[mi][ni] = __builtin_amdgcn_mfma_scale_f32_16x16x128_f8f6f4(
                    a_frag[mi].v, b_frag[ni].v, acc[mi][ni],
                    0, 0,                     // cbsz=fp8 e4m3, blgp=fp8 e4m3
                    0, 0x7F7F7F7F,            // A scales: unity E8M0
                    0, 0x7F7F7F7F);           // B scales: unity
    }

    // ---- epilogue (round-0 exact). C layout: col = l16 (-> n), row = quad*4+reg.
    __syncthreads();  // all waves done reading As/Bs; reuse LDS
    float* wred = (float*)smem + wave * (64 * 20);  // 5120 B per wave

    float s2v[4];
#pragma unroll
    for (int ni = 0; ni < 4; ++ni)
        s2v[ni] = s2[n0 + wn + ni * 16 + l16];

#pragma unroll
    for (int mi = 0; mi < 4; ++mi) {
#pragma unroll
        for (int r = 0; r < 4; ++r) {
            const int rowL = mi * 16 + quad * 4 + r;
            const float xv = x2[m0 + wm + rowL];
            float sum = 0.f;
#pragma unroll
            for (int ni = 0; ni < 4; ++ni) {
                float d2 = xv + s2v[ni] - 2.0f * acc[mi][ni][r];
                d2 = fmaxf(d2, 0.f);
                sum += __expf(-sc * d2);
            }
            wred[rowL * 20 + l16] = sum;
        }
    }
    __syncthreads();  // order LDS writes before cross-lane reads

    float4 p0 = *(float4*)(wred + lane * 20 + 0);
    float4 p1 = *(float4*)(wred + lane * 20 + 4);
    float4 p2 = *(float4*)(wred + lane * 20 + 8);
    float4 p3 = *(float4*)(wred + lane * 20 + 12);
    float s = (p0.x + p0.y + p0.z + p0.w) + (p1.x + p1.y + p1.z + p1.w)
            + (p2.x + p2.y + p2.z + p2.w) + (p3.x + p3.y + p3.z + p3.w);
    atomicAdd(&rowsum[m0 + wm + lane], s);
}

// ---------------------------------------------------------------------------
__global__ void finalize_kernel(const float* __restrict__ rowsum,
                                const float* __restrict__ scale_p,
                                float* __restrict__ out, int M, int N, int Dv) {
    const int m = blockIdx.x * 256 + threadIdx.x;
    if (m < M) {
        const float sc = *scale_p;
        const float cst = -logf((float)N) + 0.5f * (float)Dv * logf(sc / 3.14159265358979f);
        out[m] = logf(rowsum[m]) + cst;
    }
}

// ---------------------------------------------------------------------------
extern "C" void kernel_launch(void* const* d_in, const int* in_sizes, int n_in,
                              void* d_out, int out_size, void* d_ws, size_t ws_size,
                              hipStream_t stream) {
    const float* X       = (const float*)d_in[0];
    const float* S       = (const float*)d_in[1];
    const float* scale_p = (const float*)d_in[2];
    float* out = (float*)d_out;

    const int M  = out_size;            // 8192
    const int Dv = in_sizes[0] / M;     // 512
    const int N  = in_sizes[1] / Dv;    // 8192

    char* ws = (char*)d_ws;
    unsigned char* Xq = (unsigned char*)ws;
    unsigned char* Sq = (unsigned char*)(ws + (size_t)M * Dv);
    float* x2     = (float*)(ws + (size_t)M * Dv + (size_t)N * Dv);
    float* s2     = x2 + M;
    float* rowsum = s2 + N;

    prep_kernel<<<2048, 256, 0, stream>>>(X, S, Xq, Sq, x2, s2, rowsum, M, M + N, Dv);

    dim3 grid(M / BM, N / BN);
    if (Dv == 512)
        kde_gemm_kernel<512><<<grid, 256, 0, stream>>>(Xq, Sq, x2, s2, scale_p, rowsum, M, N, Dv);
    else
        kde_gemm_kernel<0><<<grid, 256, 0, stream>>>(Xq, Sq, x2, s2, scale_p, rowsum, M, N, Dv);

    finalize_kernel<<<(M + 255) / 256, 256, 0, stream>>>(rowsum, scale_p, out, M, N, Dv);
}